// Round 15
// baseline (264.203 us; speedup 1.0000x reference)
//
#include <hip/hip_runtime.h>
#include <hip/hip_bf16.h>

// InputProjection: shared LayerNorm + Q/K/V projections (fp32 in, fp32 out).
// R15: A-direct-from-global GEMM. Model from R9-R14: with A and B both via
// LDS, per-CU DS time >= MFMA time at any co-residable wave shape -> 33%
// wall. Fix: A-fragments load straight from global (64B-coalesced: 4
// hi-groups of a row share one line; k-permutation cancels A vs B since both
// assume lane=16B-contiguous k). DS now carries only B (384 cyc/CU/tile vs
// MFMA 1242/SIMD) -> MFMA-dominant at ~230 unified regs -> 2 waves/SIMD.
// 256x256 tile, 8 waves (2M x 4N), wave 128x64, BK=32, B dbuf 32 KiB,
// vmcnt(10) ledger, 1 barrier/tile.

#define HIDDEN 1024
#define NTOK   32768

typedef __bf16 bf16x8 __attribute__((ext_vector_type(8)));
typedef float  f32x4  __attribute__((ext_vector_type(4)));

#define GLOBAL_AS(p) ((const __attribute__((address_space(1))) void*)(p))
#define LDS_AS(p)    ((__attribute__((address_space(3))) void*)(p))

__device__ __forceinline__ unsigned short f2bf(float f) {
  union { float f; unsigned int i; } x; x.f = f;
  unsigned int r = x.i + 0x7FFFu + ((x.i >> 16) & 1u);   // RNE
  return (unsigned short)(r >> 16);
}

// ---------------- K1: LayerNorm (fp32 in, bf16 out) + weight cvt ----------------
__global__ __launch_bounds__(256) void ln_cvt_kernel(
    const float* __restrict__ x,
    const float* __restrict__ gamma,
    const float* __restrict__ beta,
    const float* __restrict__ wq,
    const float* __restrict__ wk,
    const float* __restrict__ wv,
    unsigned short* __restrict__ xn,
    unsigned short* __restrict__ wb) {
  const int bid = blockIdx.x;
  const int t   = threadIdx.x;
  if (bid < NTOK) {
    const size_t base = (size_t)bid * HIDDEN;
    const float4 v = ((const float4*)(x + base))[t];
    float s  = v.x + v.y + v.z + v.w;
    float s2 = v.x*v.x + v.y*v.y + v.z*v.z + v.w*v.w;
#pragma unroll
    for (int off = 32; off >= 1; off >>= 1) {
      s  += __shfl_xor(s,  off);
      s2 += __shfl_xor(s2, off);
    }
    __shared__ float red[8];
    const int w = t >> 6;
    if ((t & 63) == 0) { red[w] = s; red[4 + w] = s2; }
    __syncthreads();
    s  = red[0] + red[1] + red[2] + red[3];
    s2 = red[4] + red[5] + red[6] + red[7];
    const float mu   = s * (1.0f / HIDDEN);
    const float rstd = rsqrtf(s2 * (1.0f / HIDDEN) - mu * mu + 1e-5f);
    const float4 g  = ((const float4*)gamma)[t];
    const float4 bb = ((const float4*)beta)[t];
    ushort4 o;
    o.x = f2bf((v.x - mu) * rstd * g.x + bb.x);
    o.y = f2bf((v.y - mu) * rstd * g.y + bb.y);
    o.z = f2bf((v.z - mu) * rstd * g.z + bb.z);
    o.w = f2bf((v.w - mu) * rstd * g.w + bb.w);
    ((ushort4*)(xn + base))[t] = o;
  } else {
    const int b2 = bid - NTOK;           // 0..1535; 1024 wq, 256 wk, 256 wv
    const float* src;
    int off;
    if (b2 < 1024)      { src = wq; off = b2; }
    else if (b2 < 1280) { src = wk; off = b2 - 1024; }
    else                { src = wv; off = b2 - 1280; }
    const float4 v = ((const float4*)src)[off * 256 + t];
    ushort4 o;
    o.x = f2bf(v.x); o.y = f2bf(v.y); o.z = f2bf(v.z); o.w = f2bf(v.w);
    ((ushort4*)wb)[b2 * 256 + t] = o;
  }
}

// ---------------- K2: A-direct QKV GEMM ----------------
// 768 blocks (128 M x 6 N), 512 threads (8 waves, 2M x 4N), wave tile 128x64.
__global__ __launch_bounds__(512, 2) void qkv_gemm(
    const unsigned short* __restrict__ xn,
    const unsigned short* __restrict__ wqb,
    const float* __restrict__ bq,
    const float* __restrict__ bk,
    const float* __restrict__ bv,
    float* __restrict__ out) {
  // B double-buffer: [2][256 rows][32 k] bf16 = 16384 u16 (32 KiB).
  // Epilogue reuses this as 8 waves x 16 x 84 f32 = 43008 B -> size for max.
  __shared__ unsigned short lds[21600];
  unsigned short* Blds = lds;

  const int bid = blockIdx.x;
  const int swz = (bid & 7) * 96 + (bid >> 3);   // bijective: 768 % 8 == 0
  const int mt  = swz / 6;
  const int nt  = swz % 6;
  const int brow = mt * 256;

  const unsigned short* wbase; const float* biasptr;
  int segcol; size_t obase; int hg;
  if (nt < 4)       { wbase = wqb + (size_t)nt * 256 * HIDDEN;  biasptr = bq; segcol = nt * 256; obase = 0u;        hg = 16; }
  else if (nt == 4) { wbase = wqb + (size_t)1024 * HIDDEN;      biasptr = bk; segcol = 0;        obase = 33554432u; hg = 4;  }
  else              { wbase = wqb + (size_t)1280 * HIDDEN;      biasptr = bv; segcol = 0;        obase = 41943040u; hg = 4;  }

  const int t = threadIdx.x;
  const int w = t >> 6, lane = t & 63;
  const int wm = w >> 2, wn = w & 3;             // wave tile: rows wm*128, cols wn*64
  const int l15 = lane & 15, hi = lane >> 4;

  // ---- B staging (R9-proven): wave w covers rows 32w..32w+31, granule swizzle
  const int sr  = 2 * w * 16 + (lane >> 2);
  const int scg = ((lane & 3) ^ ((lane >> 3) & 3)) * 8;
  const unsigned short* bST = wbase + (size_t)sr * HIDDEN + scg;
  const int ldsq = 2 * w * 512;                  // wave-uniform; HW adds lane*16B

  // ---- B ds_read (proven 0-conflict): addr = buf*8192 + row*32 + (hi^((row>>1)&3))*8
  const int rdx  = (hi ^ ((l15 >> 1) & 3)) * 8;
  const int rowB = wn * 64 + l15;

  // ---- A direct from global: lane reads 16B at row (brow+wm*128+fr*16+l15),
  // k-offset hi*8. 64 lanes -> 16 x 64B fully-used segments (coalesced).
  const unsigned short* aP = xn + (size_t)(brow + wm * 128 + l15) * HIDDEN + hi * 8;

  f32x4 acc[8][4];
#pragma unroll
  for (int m = 0; m < 8; ++m)
#pragma unroll
    for (int n = 0; n < 4; ++n) acc[m][n] = (f32x4){0.f, 0.f, 0.f, 0.f};
  bf16x8 a0[8], a1[8], b[4];

#define LDA(SET, KT) do { _Pragma("unroll")                                     \
    for (int m = 0; m < 8; ++m)                                                 \
      SET[m] = *(const bf16x8*)(aP + (size_t)m * 16 * HIDDEN + (KT) * 32);      \
  } while (0)
#define STB(BUF, KT) do {                                                       \
    unsigned short* _d = Blds + (BUF) * 8192 + ldsq;                            \
    const unsigned short* _s = bST + (size_t)((KT) * 32);                       \
    __builtin_amdgcn_global_load_lds(GLOBAL_AS(_s), LDS_AS(_d), 16, 0, 0);      \
    __builtin_amdgcn_global_load_lds(GLOBAL_AS(_s + 16 * HIDDEN), LDS_AS(_d + 512), 16, 0, 0); \
  } while (0)
#define RDB(BUF) do { _Pragma("unroll")                                         \
    for (int n = 0; n < 4; ++n)                                                 \
      b[n] = *(const bf16x8*)(Blds + (BUF) * 8192 + (rowB + n * 16) * 32 + rdx);\
  } while (0)
#define MMX(SA) do { _Pragma("unroll")                                          \
    for (int m = 0; m < 8; ++m)                                                 \
      _Pragma("unroll") for (int n = 0; n < 4; ++n)                             \
        acc[m][n] = __builtin_amdgcn_mfma_f32_16x16x32_bf16(SA[m], b[n], acc[m][n], 0, 0, 0); \
  } while (0)
#define PIN __builtin_amdgcn_sched_barrier(0)
#define VMW(N) asm volatile("s_waitcnt vmcnt(" #N ")" ::: "memory")
#define LGKM0 asm volatile("s_waitcnt lgkmcnt(0)" ::: "memory")
#define BAR __builtin_amdgcn_s_barrier()

  // prologue: A(0)->a0, stage B(0)->buf0. (10 outstanding)
  LDA(a0, 0); STB(0, 0);

  // Per tile T: [issue A(T+1), Bst(T+1)] [vmcnt(10): drains A(T),Bst(T)]
  // [barrier: Bst(T) valid cross-wave] [RDB buf(T&1)] [lgkm0] [32 MFMA].
  // WAR on buf(T&1) (overwritten by Bst(T+2), issued post-MFMA(T)): margin
  // >= MFMA(621)+store-latency vs RDB window (~400 cyc) after shared barrier.
  for (int T = 0; T < 30; T += 2) {
    LDA(a1, T + 1); STB(1, T + 1); PIN; VMW(10); PIN; BAR; PIN;
    RDB(0); LGKM0; PIN; MMX(a0);
    LDA(a0, T + 2); STB(0, T + 2); PIN; VMW(10); PIN; BAR; PIN;
    RDB(1); LGKM0; PIN; MMX(a1);
  }
  // T=30
  LDA(a1, 31); STB(1, 31); PIN; VMW(10); PIN; BAR; PIN;
  RDB(0); LGKM0; PIN; MMX(a0);
  // T=31
  VMW(0); PIN; BAR; PIN;
  RDB(1); LGKM0; PIN; MMX(a1);
  BAR;   // all B-reads done before epilogue overwrites LDS

#undef LDA
#undef STB
#undef RDB
#undef MMX
#undef VMW
#undef LGKM0
#undef BAR

  // ---- epilogue (R9-proven): wave output = contiguous [128 tok][64 d] fp32.
  // Per 16-token chunk: acc+bias -> LDS (stride 84, 2-way max) -> float4
  // reads -> 1KB-contiguous stores. Per-wave-disjoint LDS regions.
  float* ep = (float*)lds;               // 8 waves x 16 x 84 f32 = 43008 B
  const int epb = w * 1344;
  const int headcol = segcol + wn * 64;
  const int gidx = headcol >> 6;
  const int tok0 = brow + wm * 128;
  const int b_ = tok0 >> 12;
  float* wout = out + obase + (size_t)(b_ * hg + gidx) * 262144u
                    + (size_t)(tok0 & 4095) * 64u;
  float biasv[4];
#pragma unroll
  for (int n = 0; n < 4; ++n) biasv[n] = biasptr[headcol + n * 16 + l15];

#pragma unroll
  for (int m = 0; m < 8; ++m) {
#pragma unroll
    for (int n = 0; n < 4; ++n)
#pragma unroll
      for (int j = 0; j < 4; ++j)
        ep[epb + (hi * 4 + j) * 84 + n * 16 + l15] = acc[m][n][j] + biasv[n];
    asm volatile("s_waitcnt lgkmcnt(0)" ::: "memory");
#pragma unroll
    for (int it = 0; it < 4; ++it) {
      const int r = it * 4 + hi;
      const float4 v = *(const float4*)(ep + epb + r * 84 + l15 * 4);
      *(float4*)(wout + (size_t)(m * 16 + r) * 64 + l15 * 4) = v;
    }
  }
#undef PIN
}

extern "C" void kernel_launch(void* const* d_in, const int* in_sizes, int n_in,
                              void* d_out, int out_size, void* d_ws, size_t ws_size,
                              hipStream_t stream) {
  const float* x  = (const float*)d_in[0];
  const float* wq = (const float*)d_in[1];
  const float* wk = (const float*)d_in[2];
  const float* wv = (const float*)d_in[3];
  const float* bq = (const float*)d_in[4];
  const float* bk = (const float*)d_in[5];
  const float* bv = (const float*)d_in[6];
  const float* g  = (const float*)d_in[7];
  const float* be = (const float*)d_in[8];
  float* out = (float*)d_out;

  unsigned short* xn = (unsigned short*)d_ws;                          // 64 MiB
  unsigned short* wb = (unsigned short*)((char*)d_ws + (64u << 20));   // 3 MiB (wq|wk|wv bf16)

  ln_cvt_kernel<<<NTOK + 1536, 256, 0, stream>>>(x, g, be, wq, wk, wv, xn, wb);
  qkv_gemm<<<768, 512, 0, stream>>>(xn, wb, bq, bk, bv, out);
}

// Round 16
// 181.368 us; speedup vs baseline: 1.4567x; 1.4567x over previous
//
#include <hip/hip_runtime.h>
#include <hip/hip_bf16.h>

// InputProjection: shared LayerNorm + Q/K/V projections (fp32 in, fp32 out).
// R16: max-TLP GEMM. Ground-truth budget: writes (32 us device-wide) rival
// DS+MFMA combined; at 1 block/CU they serialize after each K-loop. Fix:
// 128^2 tile / 4 waves / 3 LDS buffers (48 KiB) -> 3 blocks/CU co-resident,
// writes overlap other blocks' K-loops. R13's per-tile vmcnt(0) was the
// documented drain-0 anti-pattern (m218, +38-73%); now distance-2 prefetch
// with counted vmcnt(4): iter T stages tile T+2, waits only for T+1.

#define HIDDEN 1024
#define NTOK   32768

typedef __bf16 bf16x8 __attribute__((ext_vector_type(8)));
typedef float  f32x4  __attribute__((ext_vector_type(4)));

#define GLOBAL_AS(p) ((const __attribute__((address_space(1))) void*)(p))
#define LDS_AS(p)    ((__attribute__((address_space(3))) void*)(p))

__device__ __forceinline__ unsigned short f2bf(float f) {
  union { float f; unsigned int i; } x; x.f = f;
  unsigned int r = x.i + 0x7FFFu + ((x.i >> 16) & 1u);   // RNE
  return (unsigned short)(r >> 16);
}

// ---------------- K1: LayerNorm (fp32 in, bf16 out) + weight cvt ----------------
__global__ __launch_bounds__(256) void ln_cvt_kernel(
    const float* __restrict__ x,
    const float* __restrict__ gamma,
    const float* __restrict__ beta,
    const float* __restrict__ wq,
    const float* __restrict__ wk,
    const float* __restrict__ wv,
    unsigned short* __restrict__ xn,
    unsigned short* __restrict__ wb) {
  const int bid = blockIdx.x;
  const int t   = threadIdx.x;
  if (bid < NTOK) {
    const size_t base = (size_t)bid * HIDDEN;
    const float4 v = ((const float4*)(x + base))[t];
    float s  = v.x + v.y + v.z + v.w;
    float s2 = v.x*v.x + v.y*v.y + v.z*v.z + v.w*v.w;
#pragma unroll
    for (int off = 32; off >= 1; off >>= 1) {
      s  += __shfl_xor(s,  off);
      s2 += __shfl_xor(s2, off);
    }
    __shared__ float red[8];
    const int w = t >> 6;
    if ((t & 63) == 0) { red[w] = s; red[4 + w] = s2; }
    __syncthreads();
    s  = red[0] + red[1] + red[2] + red[3];
    s2 = red[4] + red[5] + red[6] + red[7];
    const float mu   = s * (1.0f / HIDDEN);
    const float rstd = rsqrtf(s2 * (1.0f / HIDDEN) - mu * mu + 1e-5f);
    const float4 g  = ((const float4*)gamma)[t];
    const float4 bb = ((const float4*)beta)[t];
    ushort4 o;
    o.x = f2bf((v.x - mu) * rstd * g.x + bb.x);
    o.y = f2bf((v.y - mu) * rstd * g.y + bb.y);
    o.z = f2bf((v.z - mu) * rstd * g.z + bb.z);
    o.w = f2bf((v.w - mu) * rstd * g.w + bb.w);
    ((ushort4*)(xn + base))[t] = o;
  } else {
    const int b2 = bid - NTOK;           // 0..1535; 1024 wq, 256 wk, 256 wv
    const float* src;
    int off;
    if (b2 < 1024)      { src = wq; off = b2; }
    else if (b2 < 1280) { src = wk; off = b2 - 1024; }
    else                { src = wv; off = b2 - 1280; }
    const float4 v = ((const float4*)src)[off * 256 + t];
    ushort4 o;
    o.x = f2bf(v.x); o.y = f2bf(v.y); o.z = f2bf(v.z); o.w = f2bf(v.w);
    ((ushort4*)wb)[b2 * 256 + t] = o;
  }
}

// ---------------- K2: max-TLP QKV GEMM ----------------
// 3072 blocks (256 M x 12 N), 256 threads (4 waves, 2M x 2N), wave tile 64x64.
__global__ __launch_bounds__(256, 3) void qkv_gemm(
    const unsigned short* __restrict__ xn,
    const unsigned short* __restrict__ wqb,
    const float* __restrict__ bq,
    const float* __restrict__ bk,
    const float* __restrict__ bv,
    float* __restrict__ out) {
  // A: [3 buf][128 rows][32 k], B same: 12288 u16 each -> 48 KiB total.
  __shared__ unsigned short lds[24576];
  unsigned short* Alds = lds;
  unsigned short* Blds = lds + 12288;

  const int bid = blockIdx.x;
  const int swz = (bid & 7) * 384 + (bid >> 3);   // bijective: 3072 % 8 == 0
  const int mt  = swz / 12;
  const int nt  = swz % 12;                        // 12 consecutive share A-panel
  const int brow = mt * 128;

  const unsigned short* wbase; const float* biasptr;
  int segcol; size_t obase; int hg;
  if (nt < 8)        { wbase = wqb + (size_t)nt * 128 * HIDDEN;                 biasptr = bq; segcol = nt * 128;        obase = 0u;        hg = 16; }
  else if (nt < 10)  { wbase = wqb + (size_t)(1024 + (nt - 8) * 128) * HIDDEN;  biasptr = bk; segcol = (nt - 8) * 128;  obase = 33554432u; hg = 4; }
  else               { wbase = wqb + (size_t)(1280 + (nt - 10) * 128) * HIDDEN; biasptr = bv; segcol = (nt - 10) * 128; obase = 41943040u; hg = 4; }

  const int t = threadIdx.x;
  const int w = t >> 6, lane = t & 63;
  const int wm = w >> 1, wn = w & 1;               // wave tile: rows wm*64, cols wn*64
  const int l15 = lane & 15, hi = lane >> 4;

  // staging (R13-proven): wave w covers rows w*32..w*32+31 (2 instr x 16 rows);
  // lane row = w*32 + (lane>>2), granule = (lane&3) ^ ((row>>1)&3)
  const int sr  = w * 32 + (lane >> 2);
  const int scg = ((lane & 3) ^ ((lane >> 3) & 3)) * 8;
  const unsigned short* aST = xn    + (size_t)(brow + sr) * HIDDEN + scg;
  const unsigned short* bST = wbase + (size_t)sr * HIDDEN + scg;
  const int ldsq = w * 1024;   // wave-uniform elems; HW adds lane*16B

  // ds_read (R13-proven): addr = buf*4096 + row*32 + (hi ^ ((row>>1)&3))*8
  const int rdx  = (hi ^ ((l15 >> 1) & 3)) * 8;
  const int rowA = wm * 64 + l15;
  const int rowB = wn * 64 + l15;

  f32x4 acc[4][4];
#pragma unroll
  for (int m = 0; m < 4; ++m)
#pragma unroll
    for (int n = 0; n < 4; ++n) acc[m][n] = (f32x4){0.f, 0.f, 0.f, 0.f};
  bf16x8 a[4], b[4];

#define ST(BUF, KT) do {                                                        \
    unsigned short* _da = Alds + (BUF) * 4096 + ldsq;                           \
    unsigned short* _db = Blds + (BUF) * 4096 + ldsq;                           \
    const unsigned short* _sa = aST + (size_t)((KT) * 32);                      \
    const unsigned short* _sb = bST + (size_t)((KT) * 32);                      \
    __builtin_amdgcn_global_load_lds(GLOBAL_AS(_sa), LDS_AS(_da), 16, 0, 0);    \
    __builtin_amdgcn_global_load_lds(GLOBAL_AS(_sa + 16 * HIDDEN), LDS_AS(_da + 512), 16, 0, 0); \
    __builtin_amdgcn_global_load_lds(GLOBAL_AS(_sb), LDS_AS(_db), 16, 0, 0);    \
    __builtin_amdgcn_global_load_lds(GLOBAL_AS(_sb + 16 * HIDDEN), LDS_AS(_db + 512), 16, 0, 0); \
  } while (0)
#define RD(BUF) do { _Pragma("unroll")                                          \
    for (int m = 0; m < 4; ++m)                                                 \
      a[m] = *(const bf16x8*)(Alds + (BUF) * 4096 + (rowA + m * 16) * 32 + rdx);\
    _Pragma("unroll")                                                           \
    for (int n = 0; n < 4; ++n)                                                 \
      b[n] = *(const bf16x8*)(Blds + (BUF) * 4096 + (rowB + n * 16) * 32 + rdx);\
  } while (0)
#define MMX do { _Pragma("unroll")                                              \
    for (int m = 0; m < 4; ++m)                                                 \
      _Pragma("unroll") for (int n = 0; n < 4; ++n)                             \
        acc[m][n] = __builtin_amdgcn_mfma_f32_16x16x32_bf16(a[m], b[n], acc[m][n], 0, 0, 0); \
  } while (0)
#define PIN __builtin_amdgcn_sched_barrier(0)
#define LGKM0 asm volatile("s_waitcnt lgkmcnt(0)" ::: "memory")
#define VMW(N) asm volatile("s_waitcnt vmcnt(" #N ")" ::: "memory")
#define BAR __builtin_amdgcn_s_barrier()

  // Iter T: {stage T+2 -> buf (T+2)%3; read tile T from buf T%3; lgkm0; MFMA;
  //          vmcnt(4): own T+1 loads done (T+2's 4 outstanding); barrier}.
  // Cross-wave: tile T valid because every wave passed vmcnt(4)+barrier at
  // end of T-1. WAR: stage(T+2) overwrites tile T-1, whose reads drained at
  // T-1's lgkm0 before that barrier.
#define STEP(BUF, SBUF, T) do {                                                 \
    ST(SBUF, (T) + 2); RD(BUF); PIN; LGKM0; PIN; MMX;                           \
    VMW(4); PIN; BAR; PIN;                                                      \
  } while (0)

  // prologue: tiles 0,1 -> bufs 0,1; validate tile 0 for all waves.
  ST(0, 0); ST(1, 1);
  VMW(4); PIN; BAR; PIN;

  for (int T = 0; T < 30; T += 3) {
    STEP(0, 2, T);
    STEP(1, 0, T + 1);
    STEP(2, 1, T + 2);
  }
  // T=30 (buf0): no stage; drain tile 31 fully.
  RD(0); PIN; LGKM0; PIN; MMX; VMW(0); PIN; BAR; PIN;
  // T=31 (buf1)
  RD(1); PIN; LGKM0; PIN; MMX;
  BAR;   // all reads done before epilogue overwrites LDS

#undef ST
#undef RD
#undef MMX
#undef STEP
#undef LGKM0
#undef VMW
#undef BAR

  // ---- epilogue (R9/R13-proven): wave output = contiguous [64 tok][64 d]
  // fp32. Per 16-token chunk: acc+bias -> LDS (stride 84, 2-way max) ->
  // float4 reads -> 1KB-contiguous stores. Per-wave-disjoint LDS regions.
  float* ep = (float*)lds;               // 4 waves x 16 x 84 f32 = 21504 B
  const int epb = w * 1344;
  const int headcol = segcol + wn * 64;
  const int gidx = headcol >> 6;
  const int tok0 = brow + wm * 64;
  const int b_ = tok0 >> 12;
  float* wout = out + obase + (size_t)(b_ * hg + gidx) * 262144u
                    + (size_t)(tok0 & 4095) * 64u;
  float biasv[4];
#pragma unroll
  for (int n = 0; n < 4; ++n) biasv[n] = biasptr[headcol + n * 16 + l15];

#pragma unroll
  for (int m = 0; m < 4; ++m) {
#pragma unroll
    for (int n = 0; n < 4; ++n)
#pragma unroll
      for (int j = 0; j < 4; ++j)
        ep[epb + (hi * 4 + j) * 84 + n * 16 + l15] = acc[m][n][j] + biasv[n];
    asm volatile("s_waitcnt lgkmcnt(0)" ::: "memory");
#pragma unroll
    for (int it = 0; it < 4; ++it) {
      const int r = it * 4 + hi;
      const float4 v = *(const float4*)(ep + epb + r * 84 + l15 * 4);
      *(float4*)(wout + (size_t)(m * 16 + r) * 64 + l15 * 4) = v;
    }
  }
#undef PIN
}

extern "C" void kernel_launch(void* const* d_in, const int* in_sizes, int n_in,
                              void* d_out, int out_size, void* d_ws, size_t ws_size,
                              hipStream_t stream) {
  const float* x  = (const float*)d_in[0];
  const float* wq = (const float*)d_in[1];
  const float* wk = (const float*)d_in[2];
  const float* wv = (const float*)d_in[3];
  const float* bq = (const float*)d_in[4];
  const float* bk = (const float*)d_in[5];
  const float* bv = (const float*)d_in[6];
  const float* g  = (const float*)d_in[7];
  const float* be = (const float*)d_in[8];
  float* out = (float*)d_out;

  unsigned short* xn = (unsigned short*)d_ws;                          // 64 MiB
  unsigned short* wb = (unsigned short*)((char*)d_ws + (64u << 20));   // 3 MiB (wq|wk|wv bf16)

  ln_cvt_kernel<<<NTOK + 1536, 256, 0, stream>>>(x, g, be, wq, wk, wv, xn, wb);
  qkv_gemm<<<3072, 256, 0, stream>>>(xn, wb, bq, bk, bv, out);
}